// Round 13
// baseline (163.928 us; speedup 1.0000x reference)
//
#include <hip/hip_runtime.h>
#include <math.h>

#define N_NODES 50000
#define N_EDGES 800000
#define DOUT 64
#define NHEAD 8
#define RP1 9            // num_relations + 1 (self-loop relation id = 8)
#define NEG_SLOPE 0.2f
#define EPS_F 1e-10f
#define M_TOT (N_EDGES + N_NODES)   // 850000 edges incl. self-loops
#define NW (RP1 * DOUT * DOUT)      // 36,864 W elements

// --- two-level bucketing (R23 config) ---
#define SUBSH 6                          // 64 nodes per subrange
#define NSUB ((N_NODES + 63) >> SUBSH)   // 782 subranges
#define SEGCAP 1536                      // lambda=1088, sigma~33
#define EPB 4096                         // per fill chunk
#define CHUNKS ((M_TOT + EPB - 1) / EPB) // 208 fill blocks
#define K1B ((N_NODES + 127) / 128)      // 391 k1 blocks (128 nodes, 8 waves)

typedef __attribute__((ext_vector_type(8))) short bf16x8;
typedef __attribute__((ext_vector_type(4))) float f32x4;

__device__ __forceinline__ unsigned short f2bf(float f) {
    unsigned int u = __float_as_uint(f);
    unsigned int r = (u + 0x7FFFu + ((u >> 16) & 1u)) >> 16;   // RNE
    return (unsigned short)r;
}
__device__ __forceinline__ float bf2f(unsigned short s) {
    return __uint_as_float(((unsigned int)s) << 16);
}

// ===========================================================================
// kprep2: W f32->bf16 + subcursor zeroing only (tiny).
// ===========================================================================
__global__ __launch_bounds__(256) void kprep2(const float* __restrict__ W,
                                              unsigned short* __restrict__ Wb,
                                              int* __restrict__ subcursor) {
    int m = blockIdx.x * 256 + threadIdx.x;
    if (m < NW / 4) {
        int i = m * 4;
        float4 v = *(const float4*)(W + i);
        ushort4 o; o.x = f2bf(v.x); o.y = f2bf(v.y); o.z = f2bf(v.z); o.w = f2bf(v.w);
        *(ushort4*)(Wb + i) = o;
    }
    if (m < NSUB) subcursor[m] = 0;
}

// ===========================================================================
// kbig (R28): R27 fold kept; hout STORE SCHEDULE fixed. R27 post-mortem:
// kbig 53->61 came from write amplification (WRITE +24MB for 14.4MB of hout:
// nine temporally-scattered 32B partial-row stores per node = L2 RMW), NOT
// bank conflicts (+0.8us device-wide). R28: dots accumulate in registers
// (dreg[9][2], rel loop unrolled so indexing is static) and all 9 float2
// stores issue back-to-back after the loop -- the node's 288B row is written
// in one contiguous burst that L2 write-combines into full lines.
// ===========================================================================
__global__ __launch_bounds__(512) void kbig(const float* __restrict__ x,
                                            const unsigned short* __restrict__ Wb,
                                            unsigned short* __restrict__ hiddenb,
                                            const int* __restrict__ node_in,
                                            const int* __restrict__ node_out,
                                            const int* __restrict__ relation,
                                            const float* __restrict__ edge_w,
                                            int* __restrict__ subcursor,
                                            int2* __restrict__ seg,
                                            const float* __restrict__ query,
                                            float* __restrict__ hout) {
    __shared__ union SM {
        unsigned short st[8 * 16 * 72];               // k1 role: 18432 B
        struct { int cnt[NSUB]; int base[NSUB]; } f;  // fill role: 6256 B
    } sm;
    __shared__ float qoq[RP1 * 64];                   // q_odd table (k1 role)
    const int t = threadIdx.x;

    if (blockIdx.x >= K1B) {
        // ---------------- fill role (two-level, unchanged) ----------------
        const int chunk = blockIdx.x - K1B;
        const int m0 = chunk * EPB;
        for (int s2 = t; s2 < NSUB; s2 += 512) sm.f.cnt[s2] = 0;
        __syncthreads();
#pragma unroll
        for (int it = 0; it < EPB / 512; it++) {
            int m = m0 + it * 512 + t;
            if (m < M_TOT) {
                int no = (m < N_EDGES) ? node_out[m] : (m - N_EDGES);
                atomicAdd(&sm.f.cnt[no >> SUBSH], 1);
            }
        }
        __syncthreads();
        for (int s2 = t; s2 < NSUB; s2 += 512) {
            int c = sm.f.cnt[s2];
            sm.f.base[s2] = (c > 0) ? atomicAdd(&subcursor[s2], c) : 0;
        }
        __syncthreads();
        for (int s2 = t; s2 < NSUB; s2 += 512) sm.f.cnt[s2] = 0;
        __syncthreads();
#pragma unroll
        for (int it = 0; it < EPB / 512; it++) {
            int m = m0 + it * 512 + t;
            if (m < M_TOT) {
                int no, ni, rl; float ew;
                if (m < N_EDGES) {
                    no = node_out[m]; ni = node_in[m];
                    rl = relation[m]; ew = edge_w[m];
                } else {
                    no = m - N_EDGES; ni = no; rl = RP1 - 1; ew = 1.0f;
                }
                int s2 = no >> SUBSH;
                int r = atomicAdd(&sm.f.cnt[s2], 1);
                int pos = sm.f.base[s2] + r;
                if (pos < SEGCAP) {
                    int2 v;
                    v.x = ni | (rl << 16) | ((no & 63) << 20);
                    v.y = __float_as_int(ew);
                    seg[(size_t)s2 * SEGCAP + pos] = v;
                }
            }
        }
        return;
    }

    // ---------------- k1 (MFMA) role + fused out-side dots ------------------
    for (int q = t; q < RP1 * 64; q += 512) {
        qoq[q] = query[(q >> 3) * 16 + 2 * (q & 7) + 1];
    }
    __syncthreads();

    const int bx = blockIdx.x;
    const int wv = t >> 6, lane = t & 63;
    const int quad = lane >> 4, l16 = lane & 15;
    const int base = bx * 128 + wv * 16;

    int arow = base + l16;
    if (arow >= N_NODES) arow = N_NODES - 1;
    const float* xr = x + (size_t)arow * 64 + quad * 8;
    const float4 f0 = *(const float4*)(xr + 0);
    const float4 f1 = *(const float4*)(xr + 4);
    const float4 f2 = *(const float4*)(xr + 32);
    const float4 f3 = *(const float4*)(xr + 36);
    bf16x8 a0, a1;
    a0[0] = (short)f2bf(f0.x); a0[1] = (short)f2bf(f0.y);
    a0[2] = (short)f2bf(f0.z); a0[3] = (short)f2bf(f0.w);
    a0[4] = (short)f2bf(f1.x); a0[5] = (short)f2bf(f1.y);
    a0[6] = (short)f2bf(f1.z); a0[7] = (short)f2bf(f1.w);
    a1[0] = (short)f2bf(f2.x); a1[1] = (short)f2bf(f2.y);
    a1[2] = (short)f2bf(f2.z); a1[3] = (short)f2bf(f2.w);
    a1[4] = (short)f2bf(f3.x); a1[5] = (short)f2bf(f3.y);
    a1[6] = (short)f2bf(f3.z); a1[7] = (short)f2bf(f3.w);

    unsigned short* sw = &sm.st[wv * 16 * 72];
    const int nl = lane >> 2;
    const int h0 = (lane & 3) * 2;
    float dreg[RP1][2];

#pragma unroll
    for (int r = 0; r < RP1; r++) {
        const unsigned short* Wr = Wb + r * 4096;
        f32x4 acc[4];
#pragma unroll
        for (int dt = 0; dt < 4; dt++) {
            const bf16x8 b0 = *(const bf16x8*)(Wr + (dt * 16 + l16) * 64 + quad * 8);
            const bf16x8 b1 = *(const bf16x8*)(Wr + (dt * 16 + l16) * 64 + quad * 8 + 32);
            f32x4 c = {0.f, 0.f, 0.f, 0.f};
            c = __builtin_amdgcn_mfma_f32_16x16x32_bf16(a0, b0, c, 0, 0, 0);
            c = __builtin_amdgcn_mfma_f32_16x16x32_bf16(a1, b1, c, 0, 0, 0);
            acc[dt] = c;
        }
#pragma unroll
        for (int dt = 0; dt < 4; dt++) {
#pragma unroll
            for (int v = 0; v < 4; v++) {
                sw[(quad * 4 + v) * 72 + dt * 16 + l16] = f2bf(acc[dt][v]);
            }
        }
        __threadfence_block();
        // hiddenb store (unchanged)
#pragma unroll
        for (int q = 0; q < 2; q++) {
            int cid = q * 64 + lane;
            int row = cid >> 3;
            int ch = cid & 7;
            int n = base + row;
            if (n < N_NODES) {
                bf16x8 v = *(const bf16x8*)(sw + row * 72 + ch * 8);
                *(bf16x8*)(hiddenb + ((size_t)r * N_NODES + n) * 64 + ch * 8) = v;
            }
        }
        // fused out-side dots -> registers (no store yet)
        {
            const unsigned short* hrow = sw + nl * 72;
            const float* q0 = &qoq[(r * 8 + h0) * 8];
            float d0 = 0.f, d1 = 0.f;
#pragma unroll
            for (int j = 0; j < 8; j++) {
                d0 += q0[j]     * bf2f(hrow[h0 * 8 + j]);
                d1 += q0[8 + j] * bf2f(hrow[h0 * 8 + 8 + j]);
            }
            dreg[r][0] = d0; dreg[r][1] = d1;
        }
        __threadfence_block();
    }

    // burst-write hout: 4 lanes cover a node's full 288B row back-to-back
    {
        int n = base + nl;
        if (n < N_NODES) {
            float* hp = hout + (size_t)n * 72 + h0;
#pragma unroll
            for (int r = 0; r < RP1; r++) {
                *(float2*)(hp + r * 8) = make_float2(dreg[r][0], dreg[r][1]);
            }
        }
    }
}

// ===========================================================================
// k3_seg (unchanged R27): physical sort + hout-based prologue (one coalesced
// 576B load per pair) + fused logits/aggregation/relu.
// ===========================================================================
__global__ __launch_bounds__(512) void k3_seg(const unsigned short* __restrict__ hiddenb,
                                              const float* __restrict__ query,
                                              const int2* __restrict__ seg,
                                              const int* __restrict__ subcursor,
                                              const float* __restrict__ hout,
                                              float* __restrict__ out) {
    __shared__ float qe[RP1 * 64];
    __shared__ int2  smeta[SEGCAP];
    __shared__ int cnt[64], start[64], cnt2[64];
    __shared__ __align__(16) float bho[8][144];

    const int t = threadIdx.x;
    const int s = blockIdx.x;
    const int scnt = min(subcursor[s], SEGCAP);

    // ---- stage this block's seg entries in registers (early, independent) --
    const int i0 = t, i1 = t + 512, i2 = t + 1024;
    int2 ev0, ev1, ev2;
    if (i0 < scnt) ev0 = seg[(size_t)s * SEGCAP + i0];
    if (i1 < scnt) ev1 = seg[(size_t)s * SEGCAP + i1];
    if (i2 < scnt) ev2 = seg[(size_t)s * SEGCAP + i2];

    for (int q = t; q < RP1 * 64; q += 512) {
        int j = q & 7, rh = q >> 3;
        qe[q] = query[rh * 16 + 2 * j];
    }
    if (t < 64) { cnt[t] = 0; cnt2[t] = 0; }
    __syncthreads();

    if (i0 < scnt) atomicAdd(&cnt[(ev0.x >> 20) & 63], 1);
    if (i1 < scnt) atomicAdd(&cnt[(ev1.x >> 20) & 63], 1);
    if (i2 < scnt) atomicAdd(&cnt[(ev2.x >> 20) & 63], 1);
    __syncthreads();

    if (t < 64) {                       // wave 0: exclusive prefix scan of cnt
        int v = cnt[t];
        int sc = v;
#pragma unroll
        for (int d = 1; d < 64; d <<= 1) {
            int o = __shfl_up(sc, d);
            if (t >= d) sc += o;
        }
        start[t] = sc - v;
    }
    __syncthreads();

    if (i0 < scnt) {
        int nol = (ev0.x >> 20) & 63;
        smeta[start[nol] + atomicAdd(&cnt2[nol], 1)] = ev0;
    }
    if (i1 < scnt) {
        int nol = (ev1.x >> 20) & 63;
        smeta[start[nol] + atomicAdd(&cnt2[nol], 1)] = ev1;
    }
    if (i2 < scnt) {
        int nol = (ev2.x >> 20) & 63;
        smeta[start[nol] + atomicAdd(&cnt2[nol], 1)] = ev2;
    }
    __syncthreads();

    const int wv = t >> 6, lane = t & 63;
    const int e_lo = lane >> 3, h = lane & 7;

    for (int k = 0; k < 4; k++) {
        const int nAl = (k * 8 + wv) * 2, nBl = nAl + 1;
        const int nA = (s << SUBSH) + nAl, nB = nA + 1;
        if (nA >= N_NODES) continue;            // wave-uniform (last subrange)

        // ---- load precomputed out-side dots: 144 contiguous floats (nA,nB) --
        if (lane < 36) {
            float4 v = *(const float4*)(hout + (size_t)nA * 72 + lane * 4);
            *(float4*)(&bho[wv][lane * 4]) = v;
        }
        __threadfence_block();

        const int cA = cnt[nAl], cB = cnt[nBl];
        const int stA = start[nAl], stB = start[nBl];
        const float degA = (float)cA, degB = (float)cB;
        const int cM = (cA > cB) ? cA : cB;

        float accA[8] = {0.f, 0.f, 0.f, 0.f, 0.f, 0.f, 0.f, 0.f};
        float accB[8] = {0.f, 0.f, 0.f, 0.f, 0.f, 0.f, 0.f, 0.f};
        float spA = 0.f, spB = 0.f;

        for (int j0 = 0; j0 < cM; j0 += 32) {
            bf16x8 rA[4], rB[4];
            int relA[4], relB[4]; float ewA[4], ewB[4];
#pragma unroll
            for (int p = 0; p < 4; p++) {
                const int sa = j0 + p * 8 + e_lo;
                if (sa < cA) {
                    int2 mv = smeta[stA + sa];
                    int ni = mv.x & 0xffff;
                    int rl = min((mv.x >> 16) & 15, RP1 - 1);   // defensive clamp
                    relA[p] = rl; ewA[p] = __int_as_float(mv.y);
                    rA[p] = *(const bf16x8*)(hiddenb + ((size_t)(rl * N_NODES + ni)) * 64 + h * 8);
                }
                if (sa < cB) {
                    int2 mv = smeta[stB + sa];
                    int ni = mv.x & 0xffff;
                    int rl = min((mv.x >> 16) & 15, RP1 - 1);   // defensive clamp
                    relB[p] = rl; ewB[p] = __int_as_float(mv.y);
                    rB[p] = *(const bf16x8*)(hiddenb + ((size_t)(rl * N_NODES + ni)) * 64 + h * 8);
                }
            }
#pragma unroll
            for (int p = 0; p < 4; p++) {
                const int sa = j0 + p * 8 + e_lo;
                if (sa < cA) {
                    const float* qp = &qe[(relA[p] * 8 + h) * 8];
                    float hif[8];
#pragma unroll
                    for (int j = 0; j < 8; j++) hif[j] = bf2f((unsigned short)rA[p][j]);
                    float wp = bho[wv][relA[p] * 8 + h];
#pragma unroll
                    for (int j = 0; j < 8; j++) wp += qp[j] * hif[j];
                    wp = (wp > 0.f) ? wp : NEG_SLOPE * wp;
                    float pa = __expf(wp) * ewA[p];
#pragma unroll
                    for (int j = 0; j < 8; j++) accA[j] += pa * hif[j];
                    spA += pa;
                }
                if (sa < cB) {
                    const float* qp = &qe[(relB[p] * 8 + h) * 8];
                    float hif[8];
#pragma unroll
                    for (int j = 0; j < 8; j++) hif[j] = bf2f((unsigned short)rB[p][j]);
                    float wp = bho[wv][72 + relB[p] * 8 + h];
#pragma unroll
                    for (int j = 0; j < 8; j++) wp += qp[j] * hif[j];
                    wp = (wp > 0.f) ? wp : NEG_SLOPE * wp;
                    float pa = __expf(wp) * ewB[p];
#pragma unroll
                    for (int j = 0; j < 8; j++) accB[j] += pa * hif[j];
                    spB += pa;
                }
            }
        }

#pragma unroll
        for (int j = 0; j < 8; j++) {
            accA[j] += __shfl_xor(accA[j], 8);
            accA[j] += __shfl_xor(accA[j], 16);
            accA[j] += __shfl_xor(accA[j], 32);
            accB[j] += __shfl_xor(accB[j], 8);
            accB[j] += __shfl_xor(accB[j], 16);
            accB[j] += __shfl_xor(accB[j], 32);
        }
        spA += __shfl_xor(spA, 8); spA += __shfl_xor(spA, 16); spA += __shfl_xor(spA, 32);
        spB += __shfl_xor(spB, 8); spB += __shfl_xor(spB, 16); spB += __shfl_xor(spB, 32);

        if (lane < 8) {
            const float sc = 1.f / ((spA / degA + EPS_F) * degA);
            float4 o0, o1;
            o0.x = fmaxf(accA[0] * sc, 0.f); o0.y = fmaxf(accA[1] * sc, 0.f);
            o0.z = fmaxf(accA[2] * sc, 0.f); o0.w = fmaxf(accA[3] * sc, 0.f);
            o1.x = fmaxf(accA[4] * sc, 0.f); o1.y = fmaxf(accA[5] * sc, 0.f);
            o1.z = fmaxf(accA[6] * sc, 0.f); o1.w = fmaxf(accA[7] * sc, 0.f);
            float* op = out + (size_t)nA * 64 + lane * 8;
            *(float4*)(op) = o0; *(float4*)(op + 4) = o1;
        } else if (lane < 16) {
            const float sc = 1.f / ((spB / degB + EPS_F) * degB);
            float4 o0, o1;
            o0.x = fmaxf(accB[0] * sc, 0.f); o0.y = fmaxf(accB[1] * sc, 0.f);
            o0.z = fmaxf(accB[2] * sc, 0.f); o0.w = fmaxf(accB[3] * sc, 0.f);
            o1.x = fmaxf(accB[4] * sc, 0.f); o1.y = fmaxf(accB[5] * sc, 0.f);
            o1.z = fmaxf(accB[6] * sc, 0.f); o1.w = fmaxf(accB[7] * sc, 0.f);
            float* op = out + (size_t)nB * 64 + (lane - 8) * 8;
            *(float4*)(op) = o0; *(float4*)(op + 4) = o1;
        }
    }
}

extern "C" void kernel_launch(void* const* d_in, const int* in_sizes, int n_in,
                              void* d_out, int out_size, void* d_ws, size_t ws_size,
                              hipStream_t stream) {
    const float* x        = (const float*)d_in[0];
    const float* W_tau    = (const float*)d_in[1];
    const float* query    = (const float*)d_in[2];
    const int*   node_in  = (const int*)d_in[3];
    const int*   node_out = (const int*)d_in[4];
    const int*   relation = (const int*)d_in[5];
    const float* edge_w   = (const float*)d_in[6];
    float* out = (float*)d_out;

    char* ws = (char*)d_ws;
    unsigned short* hiddenb   = (unsigned short*)(ws);                // 57,600,000
    unsigned short* Wb        = (unsigned short*)(ws + 57600000);     //     73,728
    int2*           seg       = (int2*)(ws + 57673728);               //  9,609,216
    int*            subcursor = (int*)(ws + 67282944);                //      3,128
    float*          hout      = (float*)(ws + 67286080);              // 14,400,000 (16B-aligned)

    // W conversion + subcursor zeroing (tiny)
    kprep2<<<(NW / 4 + 255) / 256, 256, 0, stream>>>(W_tau, Wb, subcursor);

    // merged: MFMA transform + fused out-side dots (blocks 0..K1B) overlapped
    // with two-level fill (K1B..K1B+CHUNKS)
    kbig<<<K1B + CHUNKS, 512, 0, stream>>>(x, Wb, hiddenb, node_in, node_out,
                                           relation, edge_w, subcursor, seg,
                                           query, hout);

    // per-subrange: physical sort + fused logits/agg/relu (prologue = 1 load)
    k3_seg<<<NSUB, 512, 0, stream>>>(hiddenb, query, seg, subcursor, hout, out);
}

// Round 14
// 160.040 us; speedup vs baseline: 1.0243x; 1.0243x over previous
//
#include <hip/hip_runtime.h>
#include <math.h>

#define N_NODES 50000
#define N_EDGES 800000
#define DOUT 64
#define NHEAD 8
#define RP1 9            // num_relations + 1 (self-loop relation id = 8)
#define NEG_SLOPE 0.2f
#define EPS_F 1e-10f
#define M_TOT (N_EDGES + N_NODES)   // 850000 edges incl. self-loops
#define NW (RP1 * DOUT * DOUT)      // 36,864 W elements

// --- two-level bucketing (R23 config) ---
#define SUBSH 6                          // 64 nodes per subrange
#define NSUB ((N_NODES + 63) >> SUBSH)   // 782 subranges
#define SEGCAP 1536                      // lambda=1088, sigma~33
#define EPB 4096                         // per fill chunk
#define CHUNKS ((M_TOT + EPB - 1) / EPB) // 208 fill blocks
#define K1B ((N_NODES + 127) / 128)      // 391 k1 blocks (128 nodes, 8 waves)

typedef __attribute__((ext_vector_type(8))) short bf16x8;
typedef __attribute__((ext_vector_type(4))) float f32x4;

__device__ __forceinline__ unsigned short f2bf(float f) {
    unsigned int u = __float_as_uint(f);
    unsigned int r = (u + 0x7FFFu + ((u >> 16) & 1u)) >> 16;   // RNE
    return (unsigned short)r;
}
__device__ __forceinline__ float bf2f(unsigned short s) {
    return __uint_as_float(((unsigned int)s) << 16);
}

// ===========================================================================
// kprep2: W f32->bf16 + subcursor zeroing only (tiny).
// ===========================================================================
__global__ __launch_bounds__(256) void kprep2(const float* __restrict__ W,
                                              unsigned short* __restrict__ Wb,
                                              int* __restrict__ subcursor) {
    int m = blockIdx.x * 256 + threadIdx.x;
    if (m < NW / 4) {
        int i = m * 4;
        float4 v = *(const float4*)(W + i);
        ushort4 o; o.x = f2bf(v.x); o.y = f2bf(v.y); o.z = f2bf(v.z); o.w = f2bf(v.w);
        *(ushort4*)(Wb + i) = o;
    }
    if (m < NSUB) subcursor[m] = 0;
}

// ===========================================================================
// kbig (R29): R27's low-VGPR per-rel dot+store restored; hout layout
// TRANSPOSED to [r][N][8]. R28 post-mortem: the burst-store fix worked on
// WRITE (94.5->83MB) but cost VGPR 28->128 / occupancy 33->16% (full 9x
// unroll kept nine W-load/MFMA live ranges). With [r][n][8] layout the
// per-rel immediate store IS contiguous: wave = 16 adjacent nodes x 32B
// = 512B, block = 4KB full lines -- no RMW, no unroll, no dreg.
// ===========================================================================
__global__ __launch_bounds__(512) void kbig(const float* __restrict__ x,
                                            const unsigned short* __restrict__ Wb,
                                            unsigned short* __restrict__ hiddenb,
                                            const int* __restrict__ node_in,
                                            const int* __restrict__ node_out,
                                            const int* __restrict__ relation,
                                            const float* __restrict__ edge_w,
                                            int* __restrict__ subcursor,
                                            int2* __restrict__ seg,
                                            const float* __restrict__ query,
                                            float* __restrict__ hout) {
    __shared__ union SM {
        unsigned short st[8 * 16 * 72];               // k1 role: 18432 B
        struct { int cnt[NSUB]; int base[NSUB]; } f;  // fill role: 6256 B
    } sm;
    __shared__ float qoq[RP1 * 64];                   // q_odd table (k1 role)
    const int t = threadIdx.x;

    if (blockIdx.x >= K1B) {
        // ---------------- fill role (two-level, unchanged) ----------------
        const int chunk = blockIdx.x - K1B;
        const int m0 = chunk * EPB;
        for (int s2 = t; s2 < NSUB; s2 += 512) sm.f.cnt[s2] = 0;
        __syncthreads();
#pragma unroll
        for (int it = 0; it < EPB / 512; it++) {
            int m = m0 + it * 512 + t;
            if (m < M_TOT) {
                int no = (m < N_EDGES) ? node_out[m] : (m - N_EDGES);
                atomicAdd(&sm.f.cnt[no >> SUBSH], 1);
            }
        }
        __syncthreads();
        for (int s2 = t; s2 < NSUB; s2 += 512) {
            int c = sm.f.cnt[s2];
            sm.f.base[s2] = (c > 0) ? atomicAdd(&subcursor[s2], c) : 0;
        }
        __syncthreads();
        for (int s2 = t; s2 < NSUB; s2 += 512) sm.f.cnt[s2] = 0;
        __syncthreads();
#pragma unroll
        for (int it = 0; it < EPB / 512; it++) {
            int m = m0 + it * 512 + t;
            if (m < M_TOT) {
                int no, ni, rl; float ew;
                if (m < N_EDGES) {
                    no = node_out[m]; ni = node_in[m];
                    rl = relation[m]; ew = edge_w[m];
                } else {
                    no = m - N_EDGES; ni = no; rl = RP1 - 1; ew = 1.0f;
                }
                int s2 = no >> SUBSH;
                int r = atomicAdd(&sm.f.cnt[s2], 1);
                int pos = sm.f.base[s2] + r;
                if (pos < SEGCAP) {
                    int2 v;
                    v.x = ni | (rl << 16) | ((no & 63) << 20);
                    v.y = __float_as_int(ew);
                    seg[(size_t)s2 * SEGCAP + pos] = v;
                }
            }
        }
        return;
    }

    // ---------------- k1 (MFMA) role + fused out-side dots ------------------
    for (int q = t; q < RP1 * 64; q += 512) {
        qoq[q] = query[(q >> 3) * 16 + 2 * (q & 7) + 1];
    }
    __syncthreads();

    const int bx = blockIdx.x;
    const int wv = t >> 6, lane = t & 63;
    const int quad = lane >> 4, l16 = lane & 15;
    const int base = bx * 128 + wv * 16;

    int arow = base + l16;
    if (arow >= N_NODES) arow = N_NODES - 1;
    const float* xr = x + (size_t)arow * 64 + quad * 8;
    const float4 f0 = *(const float4*)(xr + 0);
    const float4 f1 = *(const float4*)(xr + 4);
    const float4 f2 = *(const float4*)(xr + 32);
    const float4 f3 = *(const float4*)(xr + 36);
    bf16x8 a0, a1;
    a0[0] = (short)f2bf(f0.x); a0[1] = (short)f2bf(f0.y);
    a0[2] = (short)f2bf(f0.z); a0[3] = (short)f2bf(f0.w);
    a0[4] = (short)f2bf(f1.x); a0[5] = (short)f2bf(f1.y);
    a0[6] = (short)f2bf(f1.z); a0[7] = (short)f2bf(f1.w);
    a1[0] = (short)f2bf(f2.x); a1[1] = (short)f2bf(f2.y);
    a1[2] = (short)f2bf(f2.z); a1[3] = (short)f2bf(f2.w);
    a1[4] = (short)f2bf(f3.x); a1[5] = (short)f2bf(f3.y);
    a1[6] = (short)f2bf(f3.z); a1[7] = (short)f2bf(f3.w);

    unsigned short* sw = &sm.st[wv * 16 * 72];
    const int nl = lane >> 2;
    const int h0 = (lane & 3) * 2;

    for (int r = 0; r < RP1; r++) {
        const unsigned short* Wr = Wb + r * 4096;
        f32x4 acc[4];
#pragma unroll
        for (int dt = 0; dt < 4; dt++) {
            const bf16x8 b0 = *(const bf16x8*)(Wr + (dt * 16 + l16) * 64 + quad * 8);
            const bf16x8 b1 = *(const bf16x8*)(Wr + (dt * 16 + l16) * 64 + quad * 8 + 32);
            f32x4 c = {0.f, 0.f, 0.f, 0.f};
            c = __builtin_amdgcn_mfma_f32_16x16x32_bf16(a0, b0, c, 0, 0, 0);
            c = __builtin_amdgcn_mfma_f32_16x16x32_bf16(a1, b1, c, 0, 0, 0);
            acc[dt] = c;
        }
#pragma unroll
        for (int dt = 0; dt < 4; dt++) {
#pragma unroll
            for (int v = 0; v < 4; v++) {
                sw[(quad * 4 + v) * 72 + dt * 16 + l16] = f2bf(acc[dt][v]);
            }
        }
        __threadfence_block();
        // hiddenb store (unchanged)
#pragma unroll
        for (int q = 0; q < 2; q++) {
            int cid = q * 64 + lane;
            int row = cid >> 3;
            int ch = cid & 7;
            int n = base + row;
            if (n < N_NODES) {
                bf16x8 v = *(const bf16x8*)(sw + row * 72 + ch * 8);
                *(bf16x8*)(hiddenb + ((size_t)r * N_NODES + n) * 64 + ch * 8) = v;
            }
        }
        // fused out-side dots -> immediate CONTIGUOUS store ([r][n][8] layout)
        {
            const unsigned short* hrow = sw + nl * 72;
            const float* q0 = &qoq[(r * 8 + h0) * 8];
            float d0 = 0.f, d1 = 0.f;
#pragma unroll
            for (int j = 0; j < 8; j++) {
                d0 += q0[j]     * bf2f(hrow[h0 * 8 + j]);
                d1 += q0[8 + j] * bf2f(hrow[h0 * 8 + 8 + j]);
            }
            int n = base + nl;
            if (n < N_NODES) {
                *(float2*)(hout + ((size_t)r * N_NODES + n) * 8 + h0) =
                    make_float2(d0, d1);
            }
        }
        __threadfence_block();
    }
}

// ===========================================================================
// k3_seg (R29): prologue loads from transposed hout[r][n][8] -- per pair,
// 9 x 64B slab loads (rel = lane>>2, 16 floats per rel covering nA and nB).
// bho index: A = [rl*16 + h], B = [rl*16 + 8 + h]. Rest unchanged from R23.
// ===========================================================================
__global__ __launch_bounds__(512) void k3_seg(const unsigned short* __restrict__ hiddenb,
                                              const float* __restrict__ query,
                                              const int2* __restrict__ seg,
                                              const int* __restrict__ subcursor,
                                              const float* __restrict__ hout,
                                              float* __restrict__ out) {
    __shared__ float qe[RP1 * 64];
    __shared__ int2  smeta[SEGCAP];
    __shared__ int cnt[64], start[64], cnt2[64];
    __shared__ __align__(16) float bho[8][144];

    const int t = threadIdx.x;
    const int s = blockIdx.x;
    const int scnt = min(subcursor[s], SEGCAP);

    // ---- stage this block's seg entries in registers (early, independent) --
    const int i0 = t, i1 = t + 512, i2 = t + 1024;
    int2 ev0, ev1, ev2;
    if (i0 < scnt) ev0 = seg[(size_t)s * SEGCAP + i0];
    if (i1 < scnt) ev1 = seg[(size_t)s * SEGCAP + i1];
    if (i2 < scnt) ev2 = seg[(size_t)s * SEGCAP + i2];

    for (int q = t; q < RP1 * 64; q += 512) {
        int j = q & 7, rh = q >> 3;
        qe[q] = query[rh * 16 + 2 * j];
    }
    if (t < 64) { cnt[t] = 0; cnt2[t] = 0; }
    __syncthreads();

    if (i0 < scnt) atomicAdd(&cnt[(ev0.x >> 20) & 63], 1);
    if (i1 < scnt) atomicAdd(&cnt[(ev1.x >> 20) & 63], 1);
    if (i2 < scnt) atomicAdd(&cnt[(ev2.x >> 20) & 63], 1);
    __syncthreads();

    if (t < 64) {                       // wave 0: exclusive prefix scan of cnt
        int v = cnt[t];
        int sc = v;
#pragma unroll
        for (int d = 1; d < 64; d <<= 1) {
            int o = __shfl_up(sc, d);
            if (t >= d) sc += o;
        }
        start[t] = sc - v;
    }
    __syncthreads();

    if (i0 < scnt) {
        int nol = (ev0.x >> 20) & 63;
        smeta[start[nol] + atomicAdd(&cnt2[nol], 1)] = ev0;
    }
    if (i1 < scnt) {
        int nol = (ev1.x >> 20) & 63;
        smeta[start[nol] + atomicAdd(&cnt2[nol], 1)] = ev1;
    }
    if (i2 < scnt) {
        int nol = (ev2.x >> 20) & 63;
        smeta[start[nol] + atomicAdd(&cnt2[nol], 1)] = ev2;
    }
    __syncthreads();

    const int wv = t >> 6, lane = t & 63;
    const int e_lo = lane >> 3, h = lane & 7;

    for (int k = 0; k < 4; k++) {
        const int nAl = (k * 8 + wv) * 2, nBl = nAl + 1;
        const int nA = (s << SUBSH) + nAl, nB = nA + 1;
        if (nA >= N_NODES) continue;            // wave-uniform (last subrange)

        // ---- load out-side dots from hout[r][n][8]: rel = lane>>2 ----
        if (lane < 36) {
            const int rel = lane >> 2, part = lane & 3;
            float4 v = *(const float4*)(hout + ((size_t)rel * N_NODES + nA) * 8 + part * 4);
            *(float4*)(&bho[wv][rel * 16 + part * 4]) = v;
        }
        __threadfence_block();

        const int cA = cnt[nAl], cB = cnt[nBl];
        const int stA = start[nAl], stB = start[nBl];
        const float degA = (float)cA, degB = (float)cB;
        const int cM = (cA > cB) ? cA : cB;

        float accA[8] = {0.f, 0.f, 0.f, 0.f, 0.f, 0.f, 0.f, 0.f};
        float accB[8] = {0.f, 0.f, 0.f, 0.f, 0.f, 0.f, 0.f, 0.f};
        float spA = 0.f, spB = 0.f;

        for (int j0 = 0; j0 < cM; j0 += 32) {
            bf16x8 rA[4], rB[4];
            int relA[4], relB[4]; float ewA[4], ewB[4];
#pragma unroll
            for (int p = 0; p < 4; p++) {
                const int sa = j0 + p * 8 + e_lo;
                if (sa < cA) {
                    int2 mv = smeta[stA + sa];
                    int ni = mv.x & 0xffff;
                    int rl = min((mv.x >> 16) & 15, RP1 - 1);   // defensive clamp
                    relA[p] = rl; ewA[p] = __int_as_float(mv.y);
                    rA[p] = *(const bf16x8*)(hiddenb + ((size_t)(rl * N_NODES + ni)) * 64 + h * 8);
                }
                if (sa < cB) {
                    int2 mv = smeta[stB + sa];
                    int ni = mv.x & 0xffff;
                    int rl = min((mv.x >> 16) & 15, RP1 - 1);   // defensive clamp
                    relB[p] = rl; ewB[p] = __int_as_float(mv.y);
                    rB[p] = *(const bf16x8*)(hiddenb + ((size_t)(rl * N_NODES + ni)) * 64 + h * 8);
                }
            }
#pragma unroll
            for (int p = 0; p < 4; p++) {
                const int sa = j0 + p * 8 + e_lo;
                if (sa < cA) {
                    const float* qp = &qe[(relA[p] * 8 + h) * 8];
                    float hif[8];
#pragma unroll
                    for (int j = 0; j < 8; j++) hif[j] = bf2f((unsigned short)rA[p][j]);
                    float wp = bho[wv][relA[p] * 16 + h];
#pragma unroll
                    for (int j = 0; j < 8; j++) wp += qp[j] * hif[j];
                    wp = (wp > 0.f) ? wp : NEG_SLOPE * wp;
                    float pa = __expf(wp) * ewA[p];
#pragma unroll
                    for (int j = 0; j < 8; j++) accA[j] += pa * hif[j];
                    spA += pa;
                }
                if (sa < cB) {
                    const float* qp = &qe[(relB[p] * 8 + h) * 8];
                    float hif[8];
#pragma unroll
                    for (int j = 0; j < 8; j++) hif[j] = bf2f((unsigned short)rB[p][j]);
                    float wp = bho[wv][relB[p] * 16 + 8 + h];
#pragma unroll
                    for (int j = 0; j < 8; j++) wp += qp[j] * hif[j];
                    wp = (wp > 0.f) ? wp : NEG_SLOPE * wp;
                    float pa = __expf(wp) * ewB[p];
#pragma unroll
                    for (int j = 0; j < 8; j++) accB[j] += pa * hif[j];
                    spB += pa;
                }
            }
        }

#pragma unroll
        for (int j = 0; j < 8; j++) {
            accA[j] += __shfl_xor(accA[j], 8);
            accA[j] += __shfl_xor(accA[j], 16);
            accA[j] += __shfl_xor(accA[j], 32);
            accB[j] += __shfl_xor(accB[j], 8);
            accB[j] += __shfl_xor(accB[j], 16);
            accB[j] += __shfl_xor(accB[j], 32);
        }
        spA += __shfl_xor(spA, 8); spA += __shfl_xor(spA, 16); spA += __shfl_xor(spA, 32);
        spB += __shfl_xor(spB, 8); spB += __shfl_xor(spB, 16); spB += __shfl_xor(spB, 32);

        if (lane < 8) {
            const float sc = 1.f / ((spA / degA + EPS_F) * degA);
            float4 o0, o1;
            o0.x = fmaxf(accA[0] * sc, 0.f); o0.y = fmaxf(accA[1] * sc, 0.f);
            o0.z = fmaxf(accA[2] * sc, 0.f); o0.w = fmaxf(accA[3] * sc, 0.f);
            o1.x = fmaxf(accA[4] * sc, 0.f); o1.y = fmaxf(accA[5] * sc, 0.f);
            o1.z = fmaxf(accA[6] * sc, 0.f); o1.w = fmaxf(accA[7] * sc, 0.f);
            float* op = out + (size_t)nA * 64 + lane * 8;
            *(float4*)(op) = o0; *(float4*)(op + 4) = o1;
        } else if (lane < 16) {
            const float sc = 1.f / ((spB / degB + EPS_F) * degB);
            float4 o0, o1;
            o0.x = fmaxf(accB[0] * sc, 0.f); o0.y = fmaxf(accB[1] * sc, 0.f);
            o0.z = fmaxf(accB[2] * sc, 0.f); o0.w = fmaxf(accB[3] * sc, 0.f);
            o1.x = fmaxf(accB[4] * sc, 0.f); o1.y = fmaxf(accB[5] * sc, 0.f);
            o1.z = fmaxf(accB[6] * sc, 0.f); o1.w = fmaxf(accB[7] * sc, 0.f);
            float* op = out + (size_t)nB * 64 + (lane - 8) * 8;
            *(float4*)(op) = o0; *(float4*)(op + 4) = o1;
        }
    }
}

extern "C" void kernel_launch(void* const* d_in, const int* in_sizes, int n_in,
                              void* d_out, int out_size, void* d_ws, size_t ws_size,
                              hipStream_t stream) {
    const float* x        = (const float*)d_in[0];
    const float* W_tau    = (const float*)d_in[1];
    const float* query    = (const float*)d_in[2];
    const int*   node_in  = (const int*)d_in[3];
    const int*   node_out = (const int*)d_in[4];
    const int*   relation = (const int*)d_in[5];
    const float* edge_w   = (const float*)d_in[6];
    float* out = (float*)d_out;

    char* ws = (char*)d_ws;
    unsigned short* hiddenb   = (unsigned short*)(ws);                // 57,600,000
    unsigned short* Wb        = (unsigned short*)(ws + 57600000);     //     73,728
    int2*           seg       = (int2*)(ws + 57673728);               //  9,609,216
    int*            subcursor = (int*)(ws + 67282944);                //      3,128
    float*          hout      = (float*)(ws + 67286080);              // 14,400,000 ([r][n][8])

    // W conversion + subcursor zeroing (tiny)
    kprep2<<<(NW / 4 + 255) / 256, 256, 0, stream>>>(W_tau, Wb, subcursor);

    // merged: MFMA transform + fused out-side dots (blocks 0..K1B) overlapped
    // with two-level fill (K1B..K1B+CHUNKS)
    kbig<<<K1B + CHUNKS, 512, 0, stream>>>(x, Wb, hiddenb, node_in, node_out,
                                           relation, edge_w, subcursor, seg,
                                           query, hout);

    // per-subrange: physical sort + fused logits/agg/relu (hout prologue)
    k3_seg<<<NSUB, 512, 0, stream>>>(hiddenb, query, seg, subcursor, hout, out);
}